// Round 10
// baseline (193.712 us; speedup 1.0000x reference)
//
#include <hip/hip_runtime.h>
#include <hip/hip_bf16.h>
#include <math.h>

// dtypes for MFMA
typedef __bf16 bf16x8 __attribute__((ext_vector_type(8)));
typedef float  f32x16 __attribute__((ext_vector_type(16)));

// ---- workspace layout (float offsets) ----
// Total 131328 floats = EXACTLY the proven R0-R6/R9 footprint.
// accA  : [128][256] fp32                        [0, 32768)
// accX  : [128][256] fp32                        [32768, 65536)
// wlast : 256 fp32 (column 256 of conv_w)        [65536, 65792)
// wf32  : 65536 f32 (fragment-ordered conv_w)    [65792, 131328)
#define ACCA_OFF  0
#define ACCX_OFF  32768
#define WLAST_OFF 65536
#define WF_OFF    65792

// packed bf16 pair via HW cvt (memcpy: __hip_bfloat162 not trivially copyable)
static __device__ __forceinline__ unsigned pkbf(float a, float b) {
    __hip_bfloat162 h = __float22bfloat162_rn(make_float2(a, b));      // a in low 16
    unsigned u; __builtin_memcpy(&u, &h, 4); return u;
}

// Barrier WITHOUT vmcnt drain: LDS produced by reg->ds_write only (no
// global_load_lds), so lgkmcnt(0)+s_barrier is sufficient for LDS visibility
// while prefetch global->reg loads stay in flight across the barrier.
static __device__ __forceinline__ void barrier_lds() {
    asm volatile("s_waitcnt lgkmcnt(0)\n\ts_barrier" ::: "memory");
}

// DPP cross-lane add (all-VALU, no LDS pipe)
template<int CTRL, int RM>
static __device__ __forceinline__ float dpp_add(float x) {
    int yi = __builtin_amdgcn_update_dpp(0, __builtin_bit_cast(int, x), CTRL, RM, 0xF, true);
    return x + __builtin_bit_cast(float, yi);
}
// 32-lane (half-wave) sum; valid in lanes 16-31 / 48-63; lane 31/63 used.
static __device__ __forceinline__ float red32(float x) {
    x = dpp_add<0x121, 0xF>(x);   // row_ror:1
    x = dpp_add<0x122, 0xF>(x);   // row_ror:2
    x = dpp_add<0x124, 0xF>(x);   // row_ror:4
    x = dpp_add<0x128, 0xF>(x);   // row_ror:8
    x = dpp_add<0x142, 0xA>(x);   // row_bcast15 into rows 1,3
    return x;
}

// k_init: fragment-ordered f32 W + wlast + zero accumulators.
// A-frag (32x32x16): lane l holds A[o = ot*32 + (l&31)][k = S*16 + (l>>5)*8 + j].
__global__ void k_init(const float* __restrict__ conv_w, float* __restrict__ ws) {
    int idx = blockIdx.x * 256 + threadIdx.x;   // 0..65535
    int j  = idx & 7;
    int l  = (idx >> 3) & 63;
    int ot = (idx >> 9) & 7;
    int S  = idx >> 12;                         // 0..15
    int o  = ot * 32 + (l & 31);
    int k  = S * 16 + (l >> 5) * 8 + j;
    ws[WF_OFF + idx] = conv_w[o * 257 + k];     // f32, fragment order
    if (idx < 256) ws[WLAST_OFF + idx] = conv_w[idx * 257 + 256];
    ws[idx] = 0.0f;                             // zeroes accA then accX
}

// k_main: 512 blocks = 2 CO-RESIDENT 8-wave blocks per CU (the TLP fix, now
// register-honest: ~112 regs/wave < 128 cap). Block = (image xb, hw-quarter
// = 256 positions), 8 chunks of 32 hw. Fused rank-1 weights (R9-proven).
// Per-chunk DPP reduce + atomics (frees sA/sX regs); single acc (one 32-hw
// B tile). Co-resident block fills barrier tails / ds_read latency / vmcnt
// waits -- the mechanism R4's ILP couldn't give and R5/R6's spills never
// reached.
__global__ __launch_bounds__(512, 4)   // 4 waves/EU = 16 waves/CU = 2 blocks
void k_main(const float* __restrict__ x1, const float* __restrict__ x2,
            float* __restrict__ ws) {
    int bx = blockIdx.x;               // 0..511
    int xb = bx >> 2;                  // image 0..127
    int qr = bx & 3;                   // hw quarter: 256 positions
    const float* xpi = ((xb < 64) ? x1 : x2) + (size_t)(xb & 63) * (256 * 1024);
    float* accA = ws + ACCA_OFF + xb * 256;
    float* accX = ws + ACCX_OFF + xb * 256;

    int tid = threadIdx.x;
    int w = tid >> 6;                  // wave 0..7 (owns o = w*32 .. w*32+31)
    int l = tid & 63;
    int lw = l & 31, q = l >> 5;

    // [S][hw][word] bf16-pair tile, 32 hw rows; swizzle: phys = wd ^ ((hw>>2)&1)<<2
    // -> writes 2-way (free), b128 reads at wave64 floor, S-stride = 1024 B imm.
    __shared__ __align__(16) unsigned sx[16][32][8];   // 16 KB
    __shared__ __align__(16) float scen[256];          // center pixels (fold input)

    int hwi = tid & 7, kc = tid >> 3;  // thread: hw hwi*4..+3, channels {2kc,2kc+1}+128s

    // ---- prologue: chunk-0 x (HBM, issue first); centers -> LDS; W_eff fold ----
    const float* xst = xpi + qr * 256 + (size_t)(kc * 2) * 1024 + hwi * 4;
    float4 xv[4];
    #pragma unroll
    for (int s = 0; s < 2; ++s) {
        xv[2 * s]     = *(const float4*)(xst + (size_t)(128 * s) * 1024);
        xv[2 * s + 1] = *(const float4*)(xst + (size_t)(128 * s) * 1024 + 1024);
    }
    float cenv = 0.f;
    if (tid < 256) cenv = xpi[(size_t)tid * 1024 + 528];   // x[tid][16][16]
    float wl = ws[WLAST_OFF + w * 32 + lw] * (1.0f / 256.0f);
    if (tid < 256) scen[tid] = cenv;
    barrier_lds();                                     // scen visible

    // W_eff[o][k] = W[o][k] + wlast[o]*cen[k]/256, rounded to bf16 once.
    // Lane l, wave w: o = w*32+lw, k = S*16 + q*8 + j.
    const float* wf = ws + WF_OFF + (size_t)(w * 512 + l * 8);   // + S*4096
    bf16x8 A[16];
    #pragma unroll
    for (int S = 0; S < 16; ++S) {
        float4 w0 = *(const float4*)(wf + (size_t)S * 4096);
        float4 w1 = *(const float4*)(wf + (size_t)S * 4096 + 4);
        const float* cp = scen + S * 16 + q * 8;       // LDS (broadcast per q)
        float4 c0 = *(const float4*)(cp);
        float4 c1 = *(const float4*)(cp + 4);
        unsigned pw[4];
        pw[0] = pkbf(fmaf(wl, c0.x, w0.x), fmaf(wl, c0.y, w0.y));
        pw[1] = pkbf(fmaf(wl, c0.z, w0.z), fmaf(wl, c0.w, w0.w));
        pw[2] = pkbf(fmaf(wl, c1.x, w1.x), fmaf(wl, c1.y, w1.y));
        pw[3] = pkbf(fmaf(wl, c1.z, w1.z), fmaf(wl, c1.w, w1.w));
        __builtin_memcpy(&A[S], pw, 16);
    }

    int sig = ((lw >> 2) & 1) << 2;                    // 32-row swizzle (row = lw)
    const unsigned* b0p = &sx[0][lw][(q * 4) ^ sig];

    #pragma unroll 1
    for (int t = 0; t < 8; ++t) {
        if (t) barrier_lds();                          // B0: prev readers done with sx

        // ---- convert chunk t -> sx (pack + ds_write) ----
        #pragma unroll
        for (int s = 0; s < 2; ++s) {
            float4 e = xv[2 * s], o4 = xv[2 * s + 1];
            int S  = (kc >> 3) + 8 * s;
            int wd = kc & 7;
            float ee[4] = {e.x, e.y, e.z, e.w};
            float oo[4] = {o4.x, o4.y, o4.z, o4.w};
            #pragma unroll
            for (int j = 0; j < 4; ++j) {
                int jj  = (hwi + j) & 3;               // rotate rows (2-way write)
                int hwr = hwi * 4 + jj;
                sx[S][hwr][wd ^ (((hwr >> 2) & 1) << 2)] = pkbf(ee[jj], oo[jj]);
            }
        }
        // ---- prefetch chunk t+1 (in flight across barrier + MFMA + epilogue) ----
        if (t < 7) {
            const float* xn = xst + (t + 1) * 32;
            #pragma unroll
            for (int s = 0; s < 2; ++s) {
                xv[2 * s]     = *(const float4*)(xn + (size_t)(128 * s) * 1024);
                xv[2 * s + 1] = *(const float4*)(xn + (size_t)(128 * s) * 1024 + 1024);
            }
        }
        barrier_lds();                                 // B1: sx ready

        // ---- MFMA: 16 K-steps, single acc chain, pure LDS + registers ----
        f32x16 acc;
        #pragma unroll
        for (int e = 0; e < 16; ++e) acc[e] = 0.0f;
        #pragma unroll
        for (int S = 0; S < 16; ++S) {
            bf16x8 b0;
            __builtin_memcpy(&b0, b0p + S * 256, 16);  // byte off = S*1024 (imm)
            acc = __builtin_amdgcn_mfma_f32_32x32x16_bf16(A[S], b0, acc, 0, 0, 0);
        }

        // ---- epilogue chunk t (READS sx only): sigmoid; x via b64 quads;
        //      per-chunk DPP reduce + atomics (no persistent sums -> regs) ----
        #pragma unroll
        for (int m = 0; m < 4; ++m) {                  // o-quads: 4 o per b64 read
            int ob = w * 32 + 8 * m + 4 * q;           // even; quad stays in one Si
            int Si = ob >> 4;
            int Wp = ((ob >> 1) & 7) ^ sig;            // even -> b64-aligned
            unsigned u0[2];
            __builtin_memcpy(u0, &sx[Si][lw][Wp], 8);
            #pragma unroll
            for (int d = 0; d < 4; ++d) {
                int r = 4 * m + d;                     // acc idx; row = 8m+4q+d
                int o = ob + d;
                float a0s = __builtin_amdgcn_rcpf(1.0f + __expf(-acc[r]));
                unsigned wa = (d & 2) ? u0[1] : u0[0];
                float xv0 = (d & 1) ? __builtin_bit_cast(float, wa & 0xffff0000u)
                                    : __builtin_bit_cast(float, wa << 16);
                float vA = red32(a0s);
                float vX = red32(a0s * xv0);
                if (lw == 31) {                        // lanes 31,63: their own o
                    atomicAdd(&accA[o], vA);
                    atomicAdd(&accX[o], vX);
                }
            }
        }
    }
}

// out[b,o] = accX0/(accA0+eps) + accX1/(accA1+eps)
__global__ void k_out(const float* __restrict__ ws, float* __restrict__ out) {
    int idx = blockIdx.x * 256 + threadIdx.x;     // b*256 + o
    int b = idx >> 8, o = idx & 255;
    float a0 = ws[ACCA_OFF + b * 256 + o];
    float p0 = ws[ACCX_OFF + b * 256 + o];
    float a1 = ws[ACCA_OFF + (64 + b) * 256 + o];
    float p1 = ws[ACCX_OFF + (64 + b) * 256 + o];
    out[idx] = p0 / (a0 + 1e-8f) + p1 / (a1 + 1e-8f);
}

extern "C" void kernel_launch(void* const* d_in, const int* in_sizes, int n_in,
                              void* d_out, int out_size, void* d_ws, size_t ws_size,
                              hipStream_t stream) {
    const float* x1     = (const float*)d_in[0];
    const float* x2     = (const float*)d_in[1];
    const float* conv_w = (const float*)d_in[2];
    // d_in[3..6] (caLayer params) are dead: softmax over a size-1 axis == 1.
    float* ws  = (float*)d_ws;
    float* out = (float*)d_out;

    k_init<<<256, 256, 0, stream>>>(conv_w, ws);
    k_main<<<512, 512, 0, stream>>>(x1, x2, ws);
    k_out<<<64, 256, 0, stream>>>(ws, out);
}

// Round 11
// 170.276 us; speedup vs baseline: 1.1376x; 1.1376x over previous
//
#include <hip/hip_runtime.h>
#include <hip/hip_bf16.h>
#include <math.h>

// dtypes for MFMA
typedef __bf16 bf16x8 __attribute__((ext_vector_type(8)));
typedef float  f32x16 __attribute__((ext_vector_type(16)));

// ---- workspace layout (float offsets) ----
// Total 131328 floats = EXACTLY the proven R0-R6/R9 footprint.
// accA  : [128][256] fp32                        [0, 32768)
// accX  : [128][256] fp32                        [32768, 65536)
// wlast : 256 fp32 (column 256 of conv_w)        [65536, 65792)
// wf32  : 65536 f32 (fragment-ordered conv_w)    [65792, 131328)
#define ACCA_OFF  0
#define ACCX_OFF  32768
#define WLAST_OFF 65536
#define WF_OFF    65792

// packed bf16 pair via HW cvt (memcpy: __hip_bfloat162 not trivially copyable)
static __device__ __forceinline__ unsigned pkbf(float a, float b) {
    __hip_bfloat162 h = __float22bfloat162_rn(make_float2(a, b));      // a in low 16
    unsigned u; __builtin_memcpy(&u, &h, 4); return u;
}

// Barrier WITHOUT vmcnt drain: LDS produced by reg->ds_write only (no
// global_load_lds), so lgkmcnt(0)+s_barrier is sufficient for LDS visibility
// while prefetch global->reg loads stay in flight across the barrier.
static __device__ __forceinline__ void barrier_lds() {
    asm volatile("s_waitcnt lgkmcnt(0)\n\ts_barrier" ::: "memory");
}

// DPP cross-lane add (all-VALU, no LDS pipe)
template<int CTRL, int RM>
static __device__ __forceinline__ float dpp_add(float x) {
    int yi = __builtin_amdgcn_update_dpp(0, __builtin_bit_cast(int, x), CTRL, RM, 0xF, true);
    return x + __builtin_bit_cast(float, yi);
}
// 32-lane (half-wave) sum; valid in lanes 16-31 / 48-63; lane 31/63 used.
static __device__ __forceinline__ float red32(float x) {
    x = dpp_add<0x121, 0xF>(x);   // row_ror:1
    x = dpp_add<0x122, 0xF>(x);   // row_ror:2
    x = dpp_add<0x124, 0xF>(x);   // row_ror:4
    x = dpp_add<0x128, 0xF>(x);   // row_ror:8
    x = dpp_add<0x142, 0xA>(x);   // row_bcast15 into rows 1,3
    return x;
}

// k_init: fragment-ordered f32 W + wlast + zero accumulators.
// A-frag (32x32x16): lane l holds A[o = ot*32 + (l&31)][k = S*16 + (l>>5)*8 + j].
__global__ void k_init(const float* __restrict__ conv_w, float* __restrict__ ws) {
    int idx = blockIdx.x * 256 + threadIdx.x;   // 0..65535
    int j  = idx & 7;
    int l  = (idx >> 3) & 63;
    int ot = (idx >> 9) & 7;
    int S  = idx >> 12;                         // 0..15
    int o  = ot * 32 + (l & 31);
    int k  = S * 16 + (l >> 5) * 8 + j;
    ws[WF_OFF + idx] = conv_w[o * 257 + k];     // f32, fragment order
    if (idx < 256) ws[WLAST_OFF + idx] = conv_w[idx * 257 + 256];
    ws[idx] = 0.0f;                             // zeroes accA then accX
}

// k_main: R9 body VERBATIM, grid 512 instead of 256. Block = (image xb,
// hw-QUARTER = 256 positions), 4 chunks of 64 hw. R9's measured footprint
// (VGPR 96 + 32 AGPR, LDS 33.8 KB) already admits 2 co-resident 8-wave
// blocks/CU -- R9 only ran 1 because its grid was 256. This is the clean
// TLP A/B that R5/R6/R10 failed to run (they spilled chasing launch_bounds).
__global__ __launch_bounds__(512, 2)   // cap 256 regs -> no spill (proven)
void k_main(const float* __restrict__ x1, const float* __restrict__ x2,
            float* __restrict__ ws) {
    int bx = blockIdx.x;               // 0..511
    int xb = bx >> 2;                  // image 0..127
    int qr = bx & 3;                   // hw quarter: 256 positions
    const float* xpi = ((xb < 64) ? x1 : x2) + (size_t)(xb & 63) * (256 * 1024);
    float* accA = ws + ACCA_OFF + xb * 256;
    float* accX = ws + ACCX_OFF + xb * 256;

    int tid = threadIdx.x;
    int w = tid >> 6;                  // wave 0..7 (owns o = w*32 .. w*32+31)
    int l = tid & 63;
    int lw = l & 31, q = l >> 5;

    // [S][hw][word] bf16-pair tile; word swizzle: phys = logical ^ ((hw>>4)&1)<<2
    // -> writes 2-way (free), b128 reads ~4-way, S-stride = 2048 B imm.
    __shared__ __align__(16) unsigned sx[16][64][8];   // 32 KB
    __shared__ __align__(16) float scen[256];          // center pixels (fold input)

    int hwi = tid & 15, kc = tid >> 4; // thread: hw hwi*4..+3, channels {2kc,2kc+1}+64s

    // ---- prologue: chunk-0 x (HBM, issue first); centers -> LDS; W_eff fold ----
    const float* xbase = xpi + qr * 256 + (size_t)(kc * 2) * 1024 + hwi * 4;
    float4 xv[8];
    #pragma unroll
    for (int s = 0; s < 4; ++s) {
        xv[2 * s]     = *(const float4*)(xbase + (size_t)(64 * s) * 1024);
        xv[2 * s + 1] = *(const float4*)(xbase + (size_t)(64 * s + 1) * 1024);
    }
    float cenv = 0.f;
    if (tid < 256) cenv = xpi[(size_t)tid * 1024 + 528];   // x[tid][16][16]
    float wl = ws[WLAST_OFF + w * 32 + lw] * (1.0f / 256.0f);
    if (tid < 256) scen[tid] = cenv;
    barrier_lds();                                     // scen visible

    // W_eff[o][k] = W[o][k] + wlast[o]*cen[k]/256, rounded to bf16 once.
    // Lane l, wave w: o = w*32+lw, k = S*16 + q*8 + j.
    const float* wf = ws + WF_OFF + (size_t)(w * 512 + l * 8);   // + S*4096
    bf16x8 A[16];
    #pragma unroll
    for (int S = 0; S < 16; ++S) {
        float4 w0 = *(const float4*)(wf + (size_t)S * 4096);
        float4 w1 = *(const float4*)(wf + (size_t)S * 4096 + 4);
        const float* cp = scen + S * 16 + q * 8;       // LDS (broadcast per q)
        float4 c0 = *(const float4*)(cp);
        float4 c1 = *(const float4*)(cp + 4);
        unsigned pw[4];
        pw[0] = pkbf(fmaf(wl, c0.x, w0.x), fmaf(wl, c0.y, w0.y));
        pw[1] = pkbf(fmaf(wl, c0.z, w0.z), fmaf(wl, c0.w, w0.w));
        pw[2] = pkbf(fmaf(wl, c1.x, w1.x), fmaf(wl, c1.y, w1.y));
        pw[3] = pkbf(fmaf(wl, c1.z, w1.z), fmaf(wl, c1.w, w1.w));
        __builtin_memcpy(&A[S], pw, 16);
    }

    int sig = ((lw >> 4) & 1) << 2;                    // same for rows lw, 32+lw
    const unsigned* b0p = &sx[0][lw][(q * 4) ^ sig];
    const unsigned* b1p = &sx[0][32 + lw][(q * 4) ^ sig];

    float sA[16], sX[16];
    #pragma unroll
    for (int r = 0; r < 16; ++r) { sA[r] = 0.f; sX[r] = 0.f; }

    #pragma unroll 1
    for (int t = 0; t < 4; ++t) {
        if (t) barrier_lds();                          // B0: prev readers done with sx

        // ---- convert chunk t -> sx (pure pack + ds_write; no dot math) ----
        #pragma unroll
        for (int s = 0; s < 4; ++s) {
            float4 e = xv[2 * s], o4 = xv[2 * s + 1];
            int S  = (kc >> 3) + 4 * s;
            int wd = kc & 7;
            float ee[4] = {e.x, e.y, e.z, e.w};
            float oo[4] = {o4.x, o4.y, o4.z, o4.w};
            #pragma unroll
            for (int j = 0; j < 4; ++j) {
                int jj  = (hwi + j) & 3;               // rotate rows (2-way write)
                int hwr = hwi * 4 + jj;
                sx[S][hwr][wd ^ (((hwr >> 4) & 1) << 2)] = pkbf(ee[jj], oo[jj]);
            }
        }
        // ---- prefetch chunk t+1 (in flight across barrier + MFMA + epilogue) ----
        if (t < 3) {
            const float* xn = xbase + (t + 1) * 64;
            #pragma unroll
            for (int s = 0; s < 4; ++s) {
                xv[2 * s]     = *(const float4*)(xn + (size_t)(64 * s) * 1024);
                xv[2 * s + 1] = *(const float4*)(xn + (size_t)(64 * s + 1) * 1024);
            }
        }
        barrier_lds();                                 // B1: sx ready

        // ---- MFMA: 16 K-steps, pure LDS + registers ----
        f32x16 acc0, acc1;
        #pragma unroll
        for (int e = 0; e < 16; ++e) { acc0[e] = 0.0f; acc1[e] = 0.0f; }
        #pragma unroll
        for (int S = 0; S < 16; ++S) {
            bf16x8 b0, b1;
            __builtin_memcpy(&b0, b0p + S * 512, 16);  // byte off = S*2048 (imm)
            __builtin_memcpy(&b1, b1p + S * 512, 16);
            acc0 = __builtin_amdgcn_mfma_f32_32x32x16_bf16(A[S], b0, acc0, 0, 0, 0);
            acc1 = __builtin_amdgcn_mfma_f32_32x32x16_bf16(A[S], b1, acc1, 0, 0, 0);
        }

        // ---- epilogue chunk t (READS sx only -- no barrier after MFMA):
        //      z = acc; sigmoid; x via b64 quads; accumulate sA/sX regs ----
        #pragma unroll
        for (int m = 0; m < 4; ++m) {                  // o-quads: 4 o per b64 read
            int ob = w * 32 + 8 * m + 4 * q;           // even; quad stays in one Si
            int Si = ob >> 4;
            int Wp = ((ob >> 1) & 7) ^ sig;            // even -> b64-aligned
            unsigned u0[2], u1[2];
            __builtin_memcpy(u0, &sx[Si][lw][Wp], 8);
            __builtin_memcpy(u1, &sx[Si][32 + lw][Wp], 8);
            #pragma unroll
            for (int d = 0; d < 4; ++d) {
                int r = 4 * m + d;                     // acc idx; row = 8m+4q+d
                float a0s = __builtin_amdgcn_rcpf(1.0f + __expf(-acc0[r]));
                float a1s = __builtin_amdgcn_rcpf(1.0f + __expf(-acc1[r]));
                unsigned wa = (d & 2) ? u0[1] : u0[0];
                unsigned wb = (d & 2) ? u1[1] : u1[0];
                float xv0 = (d & 1) ? __builtin_bit_cast(float, wa & 0xffff0000u)
                                    : __builtin_bit_cast(float, wa << 16);
                float xv1 = (d & 1) ? __builtin_bit_cast(float, wb & 0xffff0000u)
                                    : __builtin_bit_cast(float, wb << 16);
                sA[r] += a0s + a1s;
                sX[r] += a0s * xv0 + a1s * xv1;
            }
        }
    }

    // ---- final: one DPP reduce + one atomic pair per o for the whole block ----
    // sA[r]/sX[r] with r=4m+d map to row = d+8m+4q = (r&3)+8*(r>>2)+4q.
    #pragma unroll
    for (int r = 0; r < 16; ++r) {
        int row = (r & 3) + 8 * (r >> 2) + 4 * q;
        int o = w * 32 + row;
        float rA = red32(sA[r]);
        float rX = red32(sX[r]);
        if (lw == 31) {                                // lanes 31,63 hold sums
            atomicAdd(&accA[o], rA);
            atomicAdd(&accX[o], rX);
        }
    }
}

// out[b,o] = accX0/(accA0+eps) + accX1/(accA1+eps)
__global__ void k_out(const float* __restrict__ ws, float* __restrict__ out) {
    int idx = blockIdx.x * 256 + threadIdx.x;     // b*256 + o
    int b = idx >> 8, o = idx & 255;
    float a0 = ws[ACCA_OFF + b * 256 + o];
    float p0 = ws[ACCX_OFF + b * 256 + o];
    float a1 = ws[ACCA_OFF + (64 + b) * 256 + o];
    float p1 = ws[ACCX_OFF + (64 + b) * 256 + o];
    out[idx] = p0 / (a0 + 1e-8f) + p1 / (a1 + 1e-8f);
}

extern "C" void kernel_launch(void* const* d_in, const int* in_sizes, int n_in,
                              void* d_out, int out_size, void* d_ws, size_t ws_size,
                              hipStream_t stream) {
    const float* x1     = (const float*)d_in[0];
    const float* x2     = (const float*)d_in[1];
    const float* conv_w = (const float*)d_in[2];
    // d_in[3..6] (caLayer params) are dead: softmax over a size-1 axis == 1.
    float* ws  = (float*)d_ws;
    float* out = (float*)d_out;

    k_init<<<256, 256, 0, stream>>>(conv_w, ws);
    k_main<<<512, 512, 0, stream>>>(x1, x2, ws);
    k_out<<<64, 256, 0, stream>>>(ws, out);
}

// Round 12
// 168.097 us; speedup vs baseline: 1.1524x; 1.0130x over previous
//
#include <hip/hip_runtime.h>
#include <hip/hip_bf16.h>
#include <math.h>

// dtypes for MFMA
typedef __bf16 bf16x8 __attribute__((ext_vector_type(8)));
typedef float  f32x16 __attribute__((ext_vector_type(16)));

// ---- workspace layout (float offsets) ----
// Total 131328 floats = EXACTLY the proven R0-R6/R9 footprint.
// accA  : [128][256] fp32                        [0, 32768)
// accX  : [128][256] fp32                        [32768, 65536)
// wlast : 256 fp32 (column 256 of conv_w)        [65536, 65792)
// wf32  : 65536 f32 (fragment-ordered conv_w)    [65792, 131328)
#define ACCA_OFF  0
#define ACCX_OFF  32768
#define WLAST_OFF 65536
#define WF_OFF    65792

// packed bf16 pair via HW cvt (memcpy: __hip_bfloat162 not trivially copyable)
static __device__ __forceinline__ unsigned pkbf(float a, float b) {
    __hip_bfloat162 h = __float22bfloat162_rn(make_float2(a, b));      // a in low 16
    unsigned u; __builtin_memcpy(&u, &h, 4); return u;
}

// Barrier WITHOUT vmcnt drain: LDS produced by reg->ds_write only (no
// global_load_lds), so lgkmcnt(0)+s_barrier is sufficient for LDS visibility
// while prefetch global->reg loads stay in flight across the barrier.
static __device__ __forceinline__ void barrier_lds() {
    asm volatile("s_waitcnt lgkmcnt(0)\n\ts_barrier" ::: "memory");
}

// DPP cross-lane add (all-VALU, no LDS pipe)
template<int CTRL, int RM>
static __device__ __forceinline__ float dpp_add(float x) {
    int yi = __builtin_amdgcn_update_dpp(0, __builtin_bit_cast(int, x), CTRL, RM, 0xF, true);
    return x + __builtin_bit_cast(float, yi);
}
// 32-lane (half-wave) sum; valid in lanes 16-31 / 48-63; lane 31/63 used.
static __device__ __forceinline__ float red32(float x) {
    x = dpp_add<0x121, 0xF>(x);   // row_ror:1
    x = dpp_add<0x122, 0xF>(x);   // row_ror:2
    x = dpp_add<0x124, 0xF>(x);   // row_ror:4
    x = dpp_add<0x128, 0xF>(x);   // row_ror:8
    x = dpp_add<0x142, 0xA>(x);   // row_bcast15 into rows 1,3
    return x;
}

// k_init: fragment-ordered f32 W + wlast + zero accumulators.
// A-frag (32x32x16): lane l holds A[o = ot*32 + (l&31)][k = S*16 + (l>>5)*8 + j].
__global__ void k_init(const float* __restrict__ conv_w, float* __restrict__ ws) {
    int idx = blockIdx.x * 256 + threadIdx.x;   // 0..65535
    int j  = idx & 7;
    int l  = (idx >> 3) & 63;
    int ot = (idx >> 9) & 7;
    int S  = idx >> 12;                         // 0..15
    int o  = ot * 32 + (l & 31);
    int k  = S * 16 + (l >> 5) * 8 + j;
    ws[WF_OFF + idx] = conv_w[o * 257 + k];     // f32, fragment order
    if (idx < 256) ws[WLAST_OFF + idx] = conv_w[idx * 257 + 256];
    ws[idx] = 0.0f;                             // zeroes accA then accX
}

// k_main: R9 body with ONE change -- 2-DEEP PREFETCH. Two named xv buffers
// (static indexing, rule #20); loads for chunk t+2 issue right after
// convert(t) frees that buffer, giving ~2 chunks (>15k cyc) of slack vs the
// 1-deep version's ~3k. Targets the per-chunk exposed vmcnt wait that
// survived phase-deletion (R9), ILP (R4), and TLP (R11).
__global__ __launch_bounds__(512, 2)   // cap 256 regs -> ~200 used, no spill
void k_main(const float* __restrict__ x1, const float* __restrict__ x2,
            float* __restrict__ ws) {
    int bx = blockIdx.x;               // 0..255
    int xb = bx >> 1;                  // image 0..127
    int half = bx & 1;                 // hw half: 512 positions
    const float* xpi = ((xb < 64) ? x1 : x2) + (size_t)(xb & 63) * (256 * 1024);
    float* accA = ws + ACCA_OFF + xb * 256;
    float* accX = ws + ACCX_OFF + xb * 256;

    int tid = threadIdx.x;
    int w = tid >> 6;                  // wave 0..7 (owns o = w*32 .. w*32+31)
    int l = tid & 63;
    int lw = l & 31, q = l >> 5;

    // [S][hw][word] bf16-pair tile; word swizzle: phys = logical ^ ((hw>>4)&1)<<2
    // -> writes 2-way (free), b128 reads ~4-way, S-stride = 2048 B imm.
    __shared__ __align__(16) unsigned sx[16][64][8];   // 32 KB
    __shared__ __align__(16) float scen[256];          // center pixels (fold input)

    int hwi = tid & 15, kc = tid >> 4; // thread: hw hwi*4..+3, channels {2kc,2kc+1}+64s

    const float* xbase = xpi + half * 512 + (size_t)(kc * 2) * 1024 + hwi * 4;

    // ---- prologue: chunks 0 AND 1 -> xvA/xvB; centers -> LDS; W_eff fold ----
    float4 xvA[8], xvB[8];
    #pragma unroll
    for (int s = 0; s < 4; ++s) {
        xvA[2 * s]     = *(const float4*)(xbase + (size_t)(64 * s) * 1024);
        xvA[2 * s + 1] = *(const float4*)(xbase + (size_t)(64 * s + 1) * 1024);
    }
    #pragma unroll
    for (int s = 0; s < 4; ++s) {
        xvB[2 * s]     = *(const float4*)(xbase + 64 + (size_t)(64 * s) * 1024);
        xvB[2 * s + 1] = *(const float4*)(xbase + 64 + (size_t)(64 * s + 1) * 1024);
    }
    float cenv = 0.f;
    if (tid < 256) cenv = xpi[(size_t)tid * 1024 + 528];   // x[tid][16][16]
    float wl = ws[WLAST_OFF + w * 32 + lw] * (1.0f / 256.0f);
    if (tid < 256) scen[tid] = cenv;
    barrier_lds();                                     // scen visible

    // W_eff[o][k] = W[o][k] + wlast[o]*cen[k]/256, rounded to bf16 once.
    // Lane l, wave w: o = w*32+lw, k = S*16 + q*8 + j.
    const float* wf = ws + WF_OFF + (size_t)(w * 512 + l * 8);   // + S*4096
    bf16x8 A[16];
    #pragma unroll
    for (int S = 0; S < 16; ++S) {
        float4 w0 = *(const float4*)(wf + (size_t)S * 4096);
        float4 w1 = *(const float4*)(wf + (size_t)S * 4096 + 4);
        const float* cp = scen + S * 16 + q * 8;       // LDS (broadcast per q)
        float4 c0 = *(const float4*)(cp);
        float4 c1 = *(const float4*)(cp + 4);
        unsigned pw[4];
        pw[0] = pkbf(fmaf(wl, c0.x, w0.x), fmaf(wl, c0.y, w0.y));
        pw[1] = pkbf(fmaf(wl, c0.z, w0.z), fmaf(wl, c0.w, w0.w));
        pw[2] = pkbf(fmaf(wl, c1.x, w1.x), fmaf(wl, c1.y, w1.y));
        pw[3] = pkbf(fmaf(wl, c1.z, w1.z), fmaf(wl, c1.w, w1.w));
        __builtin_memcpy(&A[S], pw, 16);
    }

    int sig = ((lw >> 4) & 1) << 2;                    // same for rows lw, 32+lw
    const unsigned* b0p = &sx[0][lw][(q * 4) ^ sig];
    const unsigned* b1p = &sx[0][32 + lw][(q * 4) ^ sig];

    float sA[16], sX[16];
    #pragma unroll
    for (int r = 0; r < 16; ++r) { sA[r] = 0.f; sX[r] = 0.f; }

    // convert: pack xv -> sx (pure pack + ds_write; rotation keeps writes 2-way)
    auto do_convert = [&](const float4 (&xv)[8]) {
        #pragma unroll
        for (int s = 0; s < 4; ++s) {
            float4 e = xv[2 * s], o4 = xv[2 * s + 1];
            int S  = (kc >> 3) + 4 * s;
            int wd = kc & 7;
            float ee[4] = {e.x, e.y, e.z, e.w};
            float oo[4] = {o4.x, o4.y, o4.z, o4.w};
            #pragma unroll
            for (int j = 0; j < 4; ++j) {
                int jj  = (hwi + j) & 3;               // rotate rows (2-way write)
                int hwr = hwi * 4 + jj;
                sx[S][hwr][wd ^ (((hwr >> 4) & 1) << 2)] = pkbf(ee[jj], oo[jj]);
            }
        }
    };
    auto do_prefetch = [&](float4 (&xv)[8], int ct) {
        const float* xn = xbase + ct * 64;
        #pragma unroll
        for (int s = 0; s < 4; ++s) {
            xv[2 * s]     = *(const float4*)(xn + (size_t)(64 * s) * 1024);
            xv[2 * s + 1] = *(const float4*)(xn + (size_t)(64 * s + 1) * 1024);
        }
    };
    auto do_mfma_epi = [&]() {
        f32x16 acc0, acc1;
        #pragma unroll
        for (int e = 0; e < 16; ++e) { acc0[e] = 0.0f; acc1[e] = 0.0f; }
        #pragma unroll
        for (int S = 0; S < 16; ++S) {
            bf16x8 b0, b1;
            __builtin_memcpy(&b0, b0p + S * 512, 16);  // byte off = S*2048 (imm)
            __builtin_memcpy(&b1, b1p + S * 512, 16);
            acc0 = __builtin_amdgcn_mfma_f32_32x32x16_bf16(A[S], b0, acc0, 0, 0, 0);
            acc1 = __builtin_amdgcn_mfma_f32_32x32x16_bf16(A[S], b1, acc1, 0, 0, 0);
        }
        // epilogue (READS sx only): sigmoid; x via b64 quads; accumulate regs
        #pragma unroll
        for (int m = 0; m < 4; ++m) {                  // o-quads: 4 o per b64 read
            int ob = w * 32 + 8 * m + 4 * q;           // even; quad stays in one Si
            int Si = ob >> 4;
            int Wp = ((ob >> 1) & 7) ^ sig;            // even -> b64-aligned
            unsigned u0[2], u1[2];
            __builtin_memcpy(u0, &sx[Si][lw][Wp], 8);
            __builtin_memcpy(u1, &sx[Si][32 + lw][Wp], 8);
            #pragma unroll
            for (int d = 0; d < 4; ++d) {
                int r = 4 * m + d;                     // acc idx; row = 8m+4q+d
                float a0s = __builtin_amdgcn_rcpf(1.0f + __expf(-acc0[r]));
                float a1s = __builtin_amdgcn_rcpf(1.0f + __expf(-acc1[r]));
                unsigned wa = (d & 2) ? u0[1] : u0[0];
                unsigned wb = (d & 2) ? u1[1] : u1[0];
                float xv0 = (d & 1) ? __builtin_bit_cast(float, wa & 0xffff0000u)
                                    : __builtin_bit_cast(float, wa << 16);
                float xv1 = (d & 1) ? __builtin_bit_cast(float, wb & 0xffff0000u)
                                    : __builtin_bit_cast(float, wb << 16);
                sA[r] += a0s + a1s;
                sX[r] += a0s * xv0 + a1s * xv1;
            }
        }
    };

    #pragma unroll 1
    for (int tt = 0; tt < 4; ++tt) {                   // 2 chunks per iteration
        // ---- chunk 2tt (buffer A) ----
        if (tt) barrier_lds();                         // B0: epilogue done with sx
        do_convert(xvA);
        if (tt < 3) do_prefetch(xvA, 2 * tt + 2);      // consumed 2 chunks later
        barrier_lds();                                 // B1: sx ready
        do_mfma_epi();
        // ---- chunk 2tt+1 (buffer B) ----
        barrier_lds();                                 // B0
        do_convert(xvB);
        if (tt < 3) do_prefetch(xvB, 2 * tt + 3);
        barrier_lds();                                 // B1
        do_mfma_epi();
    }

    // ---- final: one DPP reduce + one atomic pair per o for the whole block ----
    // sA[r]/sX[r] with r=4m+d map to row = d+8m+4q = (r&3)+8*(r>>2)+4q.
    #pragma unroll
    for (int r = 0; r < 16; ++r) {
        int row = (r & 3) + 8 * (r >> 2) + 4 * q;
        int o = w * 32 + row;
        float rA = red32(sA[r]);
        float rX = red32(sX[r]);
        if (lw == 31) {                                // lanes 31,63 hold sums
            atomicAdd(&accA[o], rA);
            atomicAdd(&accX[o], rX);
        }
    }
}

// out[b,o] = accX0/(accA0+eps) + accX1/(accA1+eps)
__global__ void k_out(const float* __restrict__ ws, float* __restrict__ out) {
    int idx = blockIdx.x * 256 + threadIdx.x;     // b*256 + o
    int b = idx >> 8, o = idx & 255;
    float a0 = ws[ACCA_OFF + b * 256 + o];
    float p0 = ws[ACCX_OFF + b * 256 + o];
    float a1 = ws[ACCA_OFF + (64 + b) * 256 + o];
    float p1 = ws[ACCX_OFF + (64 + b) * 256 + o];
    out[idx] = p0 / (a0 + 1e-8f) + p1 / (a1 + 1e-8f);
}

extern "C" void kernel_launch(void* const* d_in, const int* in_sizes, int n_in,
                              void* d_out, int out_size, void* d_ws, size_t ws_size,
                              hipStream_t stream) {
    const float* x1     = (const float*)d_in[0];
    const float* x2     = (const float*)d_in[1];
    const float* conv_w = (const float*)d_in[2];
    // d_in[3..6] (caLayer params) are dead: softmax over a size-1 axis == 1.
    float* ws  = (float*)d_ws;
    float* out = (float*)d_out;

    k_init<<<256, 256, 0, stream>>>(conv_w, ws);
    k_main<<<256, 512, 0, stream>>>(x1, x2, ws);
    k_out<<<64, 256, 0, stream>>>(ws, out);
}